// Round 1
// baseline (240.704 us; speedup 1.0000x reference)
//
#include <hip/hip_runtime.h>

#define Bq 8
#define Sq 1024
#define Dq 512

typedef __attribute__((ext_vector_type(8))) short bf16x8;
typedef __attribute__((ext_vector_type(4))) float f32x4;

__device__ __forceinline__ unsigned short f2bf(float f) {
  unsigned int u = __float_as_uint(f);
  return (unsigned short)((u + 0x7fffu + ((u >> 16) & 1u)) >> 16);
}

// ---- elementwise fp32 -> bf16 cast (n must be multiple of 1024; grid = n/1024) ----
__global__ void convert_bf(const float* __restrict__ src, unsigned short* __restrict__ dst) {
  int i = (blockIdx.x * blockDim.x + threadIdx.x) * 4;
  float4 v = *(const float4*)(src + i);
  ushort4 o;
  o.x = f2bf(v.x); o.y = f2bf(v.y); o.z = f2bf(v.z); o.w = f2bf(v.w);
  *(ushort4*)(dst + i) = o;
}

// ---- colsum[b][d] = sum_t inp[b][t][d]  (atomic partials; colsum pre-zeroed) ----
__global__ void colsum_kernel(const float* __restrict__ inp, float* __restrict__ colsum) {
  int b = blockIdx.z;
  int d = blockIdx.x * 256 + threadIdx.x;
  int t0 = blockIdx.y * 128;
  const float* p = inp + ((size_t)b * Sq + t0) * Dq + d;
  float s = 0.f;
#pragma unroll 8
  for (int t = 0; t < 128; ++t) s += p[(size_t)t * Dq];
  atomicAdd(&colsum[b * Dq + d], s);
}

// ---- inpT[b][d][t] = bf16(inp[b][t][d]) ----
__global__ void transpose_bf(const float* __restrict__ inp, unsigned short* __restrict__ inpT) {
  __shared__ unsigned short tile[32][33];
  int b = blockIdx.z;
  int t0 = blockIdx.x * 32, d0 = blockIdx.y * 32;
  int tx = threadIdx.x, ty = threadIdx.y;  // 32 x 8
  const float* src = inp + (size_t)b * Sq * Dq;
#pragma unroll
  for (int i = 0; i < 4; ++i)
    tile[ty + i * 8][tx] = f2bf(src[(size_t)(t0 + ty + i * 8) * Dq + d0 + tx]);
  __syncthreads();
  unsigned short* dst = inpT + (size_t)b * Dq * Sq;
#pragma unroll
  for (int i = 0; i < 4; ++i)
    dst[(size_t)(d0 + ty + i * 8) * Sq + t0 + tx] = tile[tx][ty + i * 8];
}

// ---- fac[b*S+s] = mask / (scale * (dot(aspect[s],colsum)/scale + 1e-4)) ----
__global__ void fac_kernel(const float* __restrict__ aspect, const float* __restrict__ colsum,
                           const float* __restrict__ lenv, float* __restrict__ fac) {
  int row = blockIdx.x * 4 + (threadIdx.x >> 6);
  int lane = threadIdx.x & 63;
  int b = row >> 10, s = row & 1023;
  const float* a = aspect + (size_t)row * Dq;
  const float* c = colsum + b * Dq;
  float sum = 0.f;
  int base = lane * 8;
#pragma unroll
  for (int i = 0; i < 8; ++i) sum += a[base + i] * c[base + i];
#pragma unroll
  for (int o = 32; o; o >>= 1) sum += __shfl_xor(sum, o, 64);
  if (lane == 0) {
    float len = lenv[b];
    float scale = sqrtf(len);
    float f = 0.f;
    if (s < (int)len) {
      float rowsum = sum / scale;
      f = 1.f / (scale * (rowsum + 1e-4f));
    }
    fac[row] = f;
  }
}

// ---- tiled bf16 MFMA GEMM: C[M][N] = A[M][K] * B[N][K]^T, epilogue per EPI ----
struct EpiArgs {
  const float* fac;
  const float* inp;
  const float* aspect;
  const float* lenv;
  const float* bias;
  const float* resid;
  float* outF;
  unsigned short* outBf;
};

template <int EPI>
__global__ __launch_bounds__(256) void gemm_bf16(
    const unsigned short* __restrict__ Ag, const unsigned short* __restrict__ Bg,
    int M, int N, int K, long strideA, long strideB, long strideOF, long strideOBf,
    EpiArgs e) {
  __shared__ unsigned short sA[128 * 40];
  __shared__ unsigned short sB[128 * 40];
  int b = blockIdx.z;
  int bn = blockIdx.x, bm = blockIdx.y;
  const unsigned short* Ab = Ag + (size_t)b * strideA + (size_t)bm * 128 * K;
  const unsigned short* Bb = Bg + (size_t)b * strideB + (size_t)bn * 128 * K;
  int tid = threadIdx.x;
  int lane = tid & 63, wave = tid >> 6;
  int wm = (wave >> 1) * 64, wn = (wave & 1) * 64;
  int lr = lane & 15, lq = lane >> 4;

  f32x4 acc[4][4] = {};

  for (int k0 = 0; k0 < K; k0 += 32) {
#pragma unroll
    for (int c = 0; c < 2; ++c) {
      int linear = tid * 8 + c * 2048;
      int r = linear >> 5, kk = linear & 31;
      *(bf16x8*)&sA[r * 40 + kk] = *(const bf16x8*)&Ab[(size_t)r * K + k0 + kk];
      *(bf16x8*)&sB[r * 40 + kk] = *(const bf16x8*)&Bb[(size_t)r * K + k0 + kk];
    }
    __syncthreads();
    bf16x8 af[4], bfr[4];
#pragma unroll
    for (int mi = 0; mi < 4; ++mi)
      af[mi] = *(const bf16x8*)&sA[(wm + mi * 16 + lr) * 40 + lq * 8];
#pragma unroll
    for (int ni = 0; ni < 4; ++ni)
      bfr[ni] = *(const bf16x8*)&sB[(wn + ni * 16 + lr) * 40 + lq * 8];
#pragma unroll
    for (int mi = 0; mi < 4; ++mi)
#pragma unroll
      for (int ni = 0; ni < 4; ++ni)
        acc[mi][ni] = __builtin_amdgcn_mfma_f32_16x16x32_bf16(af[mi], bfr[ni], acc[mi][ni], 0, 0, 0);
    __syncthreads();
  }

#pragma unroll
  for (int mi = 0; mi < 4; ++mi) {
#pragma unroll
    for (int ni = 0; ni < 4; ++ni) {
#pragma unroll
      for (int i = 0; i < 4; ++i) {
        int r = bm * 128 + wm + mi * 16 + lq * 4 + i;
        int cc = bn * 128 + wn + ni * 16 + lr;
        float v = acc[mi][ni][i];
        if (EPI == 1) {
          float f = e.fac[(size_t)b * M + r];
          e.outBf[(size_t)b * strideOBf + (size_t)r * N + cc] = f2bf(v * f);
        } else if (EPI == 2) {
          int len = (int)e.lenv[b];
          size_t idx = (size_t)b * ((size_t)Sq * Dq) + (size_t)r * Dq + cc;
          float add = (r < len) ? (e.inp[idx] + e.aspect[idx]) : 0.f;
          float o = v + add;
          e.outF[(size_t)b * strideOF + (size_t)r * N + cc] = o;
          e.outBf[(size_t)b * strideOBf + (size_t)r * N + cc] = f2bf(o);
        } else if (EPI == 3) {
          float o = fmaxf(v + e.bias[cc], 0.f);
          e.outBf[(size_t)r * N + cc] = f2bf(o);
        } else {
          float o = fmaxf(v + e.bias[cc], 0.f);
          size_t idx = (size_t)r * N + cc;
          e.outF[idx] = 2.f * e.resid[idx] + o;
        }
      }
    }
  }
}

// ---- out[row] = final[row] / ||final[row]|| over D=512; 4 rows per block ----
__global__ void norm_kernel(const float* __restrict__ fin, float* __restrict__ out) {
  int row = blockIdx.x * 4 + (threadIdx.x >> 6);
  int lane = threadIdx.x & 63;
  const float* p = fin + (size_t)row * Dq;
  float4 v0 = *(const float4*)(p + lane * 8);
  float4 v1 = *(const float4*)(p + lane * 8 + 4);
  float ss = v0.x * v0.x + v0.y * v0.y + v0.z * v0.z + v0.w * v0.w +
             v1.x * v1.x + v1.y * v1.y + v1.z * v1.z + v1.w * v1.w;
#pragma unroll
  for (int o = 32; o; o >>= 1) ss += __shfl_xor(ss, o, 64);
  float rn = 1.f / sqrtf(ss);
  float* q = out + (size_t)row * Dq;
  v0.x *= rn; v0.y *= rn; v0.z *= rn; v0.w *= rn;
  v1.x *= rn; v1.y *= rn; v1.z *= rn; v1.w *= rn;
  *(float4*)(q + lane * 8) = v0;
  *(float4*)(q + lane * 8 + 4) = v1;
}

extern "C" void kernel_launch(void* const* d_in, const int* in_sizes, int n_in,
                              void* d_out, int out_size, void* d_ws, size_t ws_size,
                              hipStream_t stream) {
  const float* inp = (const float*)d_in[0];
  const float* inp_len = (const float*)d_in[1];
  const float* aspect = (const float*)d_in[2];
  const float* w1 = (const float*)d_in[3];
  const float* b1 = (const float*)d_in[4];
  const float* w2 = (const float*)d_in[5];
  const float* b2 = (const float*)d_in[6];
  float* out = (float*)d_out;

  char* W = (char*)d_ws;
  const size_t MB = 1ull << 20;
  unsigned short* inp_bf = (unsigned short*)(W + 0);        // 8 MB  [B][S][D]
  unsigned short* asp_bf = (unsigned short*)(W + 8 * MB);   // 8 MB  [B][S][D]
  unsigned short* inpT   = (unsigned short*)(W + 16 * MB);  // 8 MB  [B][D][S]
  unsigned short* att    = (unsigned short*)(W + 24 * MB);  // 16 MB [B][S][S] (bf16)
  float*          finalF = (float*)(W + 24 * MB);           // 16 MB (reuses att after GEMM2)
  float*          ffnF   = (float*)(W + 40 * MB);           // 16 MB [B*S][D]
  unsigned short* ffnBf  = (unsigned short*)(W + 56 * MB);  // 8 MB
  unsigned short* o1b    = (unsigned short*)(W + 64 * MB);  // 8 MB
  unsigned short* w1bf   = (unsigned short*)(W + 72 * MB);  // 512 KB
  unsigned short* w2bf   = (unsigned short*)(W + 72 * MB + 512 * 1024);
  float*          colsum = (float*)(W + 73 * MB);           // 16 KB
  float*          fac    = (float*)(W + 73 * MB + 64 * 1024);  // 32 KB

  // prep
  convert_bf<<<4096, 256, 0, stream>>>(inp, inp_bf);
  convert_bf<<<4096, 256, 0, stream>>>(aspect, asp_bf);
  convert_bf<<<256, 256, 0, stream>>>(w1, w1bf);
  convert_bf<<<256, 256, 0, stream>>>(w2, w2bf);
  hipMemsetAsync(colsum, 0, Bq * Dq * sizeof(float), stream);
  colsum_kernel<<<dim3(2, 8, 8), 256, 0, stream>>>(inp, colsum);
  transpose_bf<<<dim3(32, 16, 8), dim3(32, 8), 0, stream>>>(inp, inpT);
  fac_kernel<<<2048, 256, 0, stream>>>(aspect, colsum, inp_len, fac);

  // GEMM1: att_n[b][s][t] = (aspect[s]·inp[t]) * fac[b][s]   M=1024 N=1024 K=512
  {
    EpiArgs e{};
    e.fac = fac; e.outBf = att;
    gemm_bf16<1><<<dim3(8, 8, 8), 256, 0, stream>>>(
        asp_bf, inp_bf, 1024, 1024, 512,
        (long)Sq * Dq, (long)Sq * Dq, 0, (long)Sq * Sq, e);
  }
  // GEMM2: ffn_inp = att_n @ inp + (inp+aspect)*mask        M=1024 N=512 K=1024
  {
    EpiArgs e{};
    e.inp = inp; e.aspect = aspect; e.lenv = inp_len; e.outF = ffnF; e.outBf = ffnBf;
    gemm_bf16<2><<<dim3(4, 8, 8), 256, 0, stream>>>(
        att, inpT, 1024, 512, 1024,
        (long)Sq * Sq, (long)Dq * Sq, (long)Sq * Dq, (long)Sq * Dq, e);
  }
  // GEMM3: o1 = relu(ffn @ w1^T + b1)                        M=8192 N=512 K=512
  {
    EpiArgs e{};
    e.bias = b1; e.outBf = o1b;
    gemm_bf16<3><<<dim3(4, 64, 1), 256, 0, stream>>>(
        ffnBf, w1bf, 8192, 512, 512, 0, 0, 0, 0, e);
  }
  // GEMM4: final = 2*ffn + relu(o1 @ w2^T + b2)              M=8192 N=512 K=512
  {
    EpiArgs e{};
    e.bias = b2; e.resid = ffnF; e.outF = finalF;
    gemm_bf16<4><<<dim3(4, 64, 1), 256, 0, stream>>>(
        o1b, w2bf, 8192, 512, 512, 0, 0, 0, 0, e);
  }
  // normalize rows
  norm_kernel<<<2048, 256, 0, stream>>>(finalF, out);
}

// Round 2
// 227.913 us; speedup vs baseline: 1.0561x; 1.0561x over previous
//
#include <hip/hip_runtime.h>

#define Bq 8
#define Sq 1024
#define Dq 512

typedef __attribute__((ext_vector_type(8))) short bf16x8;
typedef __attribute__((ext_vector_type(4))) float f32x4;

__device__ __forceinline__ unsigned short f2bf(float f) {
  unsigned int u = __float_as_uint(f);
  return (unsigned short)((u + 0x7fffu + ((u >> 16) & 1u)) >> 16);
}

__device__ __forceinline__ void load_lds16(const unsigned short* g, unsigned short* l) {
  __builtin_amdgcn_global_load_lds(
      (const __attribute__((address_space(1))) unsigned int*)g,
      (__attribute__((address_space(3))) unsigned int*)l, 16, 0, 0);
}

// ---- small fp32 -> bf16 cast for weights ----
__global__ void convert_bf(const float* __restrict__ src, unsigned short* __restrict__ dst) {
  int i = (blockIdx.x * blockDim.x + threadIdx.x) * 4;
  float4 v = *(const float4*)(src + i);
  ushort4 o;
  o.x = f2bf(v.x); o.y = f2bf(v.y); o.z = f2bf(v.z); o.w = f2bf(v.w);
  *(ushort4*)(dst + i) = o;
}

// ---- fused inp pass: bf16 cast + transpose + colsum partials ----
__global__ void prep_inp(const float* __restrict__ inp, unsigned short* __restrict__ inp_bf,
                         unsigned short* __restrict__ inpT, float* __restrict__ colsum) {
  __shared__ unsigned short tile[32][33];
  __shared__ float csum[8][33];
  int b = blockIdx.z;
  int t0 = blockIdx.x * 32, d0 = blockIdx.y * 32;
  int tx = threadIdx.x, ty = threadIdx.y;  // 32 x 8
  const float* src = inp + ((size_t)b * Sq + t0) * Dq + d0;
  unsigned short* dbf = inp_bf + ((size_t)b * Sq + t0) * Dq + d0;
  float part = 0.f;
#pragma unroll
  for (int i = 0; i < 4; ++i) {
    float v = src[(size_t)(ty + i * 8) * Dq + tx];
    unsigned short h = f2bf(v);
    tile[ty + i * 8][tx] = h;
    dbf[(size_t)(ty + i * 8) * Dq + tx] = h;
    part += v;
  }
  csum[ty][tx] = part;
  __syncthreads();
  unsigned short* dst = inpT + (size_t)b * Dq * Sq;
#pragma unroll
  for (int i = 0; i < 4; ++i)
    dst[(size_t)(d0 + ty + i * 8) * Sq + t0 + tx] = tile[tx][ty + i * 8];
  if (ty == 0) {
    float s = 0.f;
#pragma unroll
    for (int i = 0; i < 8; ++i) s += csum[i][tx];
    atomicAdd(&colsum[b * Dq + d0 + tx], s);
  }
}

// ---- fused aspect pass: bf16 cast + exact fp32 fac ----
__global__ void prep_asp(const float* __restrict__ aspect, const float* __restrict__ colsum,
                         const float* __restrict__ lenv, unsigned short* __restrict__ asp_bf,
                         float* __restrict__ fac) {
  int row = blockIdx.x * 4 + (threadIdx.x >> 6);
  int lane = threadIdx.x & 63;
  int b = row >> 10, s = row & 1023;
  const float* a = aspect + (size_t)row * Dq + lane * 8;
  const float* c = colsum + b * Dq + lane * 8;
  float4 a0 = *(const float4*)a, a1 = *(const float4*)(a + 4);
  float4 c0 = *(const float4*)c, c1 = *(const float4*)(c + 4);
  float sum = a0.x * c0.x + a0.y * c0.y + a0.z * c0.z + a0.w * c0.w +
              a1.x * c1.x + a1.y * c1.y + a1.z * c1.z + a1.w * c1.w;
  ushort4 o0; o0.x = f2bf(a0.x); o0.y = f2bf(a0.y); o0.z = f2bf(a0.z); o0.w = f2bf(a0.w);
  ushort4 o1; o1.x = f2bf(a1.x); o1.y = f2bf(a1.y); o1.z = f2bf(a1.z); o1.w = f2bf(a1.w);
  unsigned short* dst = asp_bf + (size_t)row * Dq + lane * 8;
  *(ushort4*)dst = o0;
  *(ushort4*)(dst + 4) = o1;
#pragma unroll
  for (int o = 32; o; o >>= 1) sum += __shfl_xor(sum, o, 64);
  if (lane == 0) {
    float len = lenv[b];
    float scale = sqrtf(len);
    float f = 0.f;
    if (s < (int)len) f = 1.f / (scale * (sum / scale + 1e-4f));
    fac[row] = f;
  }
}

// ---- m97-style bf16 MFMA GEMM: C[M][N] = A[M][K] * B[N][K]^T ----
// 128M x 64N tile, 4 waves (each 64x32), BK=32, global_load_lds staging,
// frag-major LDS (16B granule g: A g = lq*128+row, B g = lq*64+row) so both
// staging writes and ds_read_b128 frag reads are bank-conflict-free.
struct EpiArgs {
  const float* fac;
  const float* inp;
  const float* aspect;
  const float* lenv;
  const float* bias;
  const float* resid;
  float* outF;
  unsigned short* outBf;
};

template <int EPI>
__global__ __launch_bounds__(256, 4) void gemm_bf16(
    const unsigned short* __restrict__ Ag, const unsigned short* __restrict__ Bg,
    int M, int N, int K, long strideA, long strideB, long strideOF, long strideOBf,
    EpiArgs e) {
  __shared__ unsigned short sA[128 * 32];  // 8 KB
  __shared__ unsigned short sB[64 * 32];   // 4 KB
  int b = blockIdx.z;
  int bn = blockIdx.x, bm = blockIdx.y;
  const unsigned short* Ab = Ag + (size_t)b * strideA + (size_t)bm * 128 * K;
  const unsigned short* Bb = Bg + (size_t)b * strideB + (size_t)bn * 64 * K;
  int tid = threadIdx.x;
  int lane = tid & 63, wave = tid >> 6;
  int wm = (wave >> 1) * 64, wn = (wave & 1) * 32;
  int lr = lane & 15, lq = lane >> 4;

  // staging: slot s (16B granule) <- lane-consecutive LDS, gather global
  int a0row = tid & 127, a0q = tid >> 7;          // slots 0..255
  int a1row = tid & 127, a1q = (tid >> 7) + 2;    // slots 256..511
  int brow = tid & 63, bq = tid >> 6;             // slots 0..255
  const unsigned short* gA0 = Ab + (size_t)a0row * K + a0q * 8;
  const unsigned short* gA1 = Ab + (size_t)a1row * K + a1q * 8;
  const unsigned short* gB = Bb + (size_t)brow * K + bq * 8;
  unsigned short* lA0 = &sA[(size_t)tid * 8];
  unsigned short* lA1 = &sA[(size_t)(tid + 256) * 8];
  unsigned short* lB = &sB[(size_t)tid * 8];

  f32x4 acc[4][2] = {};

  for (int k0 = 0; k0 < K; k0 += 32) {
    load_lds16(gA0 + k0, lA0);
    load_lds16(gA1 + k0, lA1);
    load_lds16(gB + k0, lB);
    __syncthreads();
    bf16x8 af[4], bfr[2];
#pragma unroll
    for (int mi = 0; mi < 4; ++mi)
      af[mi] = *(const bf16x8*)&sA[(size_t)(lq * 128 + wm + mi * 16 + lr) * 8];
#pragma unroll
    for (int ni = 0; ni < 2; ++ni)
      bfr[ni] = *(const bf16x8*)&sB[(size_t)(lq * 64 + wn + ni * 16 + lr) * 8];
#pragma unroll
    for (int mi = 0; mi < 4; ++mi)
#pragma unroll
      for (int ni = 0; ni < 2; ++ni)
        acc[mi][ni] = __builtin_amdgcn_mfma_f32_16x16x32_bf16(af[mi], bfr[ni], acc[mi][ni], 0, 0, 0);
    __syncthreads();
  }

#pragma unroll
  for (int mi = 0; mi < 4; ++mi) {
#pragma unroll
    for (int ni = 0; ni < 2; ++ni) {
#pragma unroll
      for (int i = 0; i < 4; ++i) {
        int r = bm * 128 + wm + mi * 16 + lq * 4 + i;
        int cc = bn * 64 + wn + ni * 16 + lr;
        float v = acc[mi][ni][i];
        if (EPI == 1) {
          float f = e.fac[(size_t)b * M + r];
          e.outBf[(size_t)b * strideOBf + (size_t)r * N + cc] = f2bf(v * f);
        } else if (EPI == 2) {
          int len = (int)e.lenv[b];
          size_t idx = (size_t)b * ((size_t)Sq * Dq) + (size_t)r * Dq + cc;
          float add = (r < len) ? (e.inp[idx] + e.aspect[idx]) : 0.f;
          float o = v + add;
          e.outF[(size_t)b * strideOF + (size_t)r * N + cc] = o;
          e.outBf[(size_t)b * strideOBf + (size_t)r * N + cc] = f2bf(o);
        } else if (EPI == 3) {
          float o = fmaxf(v + e.bias[cc], 0.f);
          e.outBf[(size_t)r * N + cc] = f2bf(o);
        } else {
          float o = fmaxf(v + e.bias[cc], 0.f);
          size_t idx = (size_t)r * N + cc;
          e.outF[idx] = 2.f * e.resid[idx] + o;
        }
      }
    }
  }
}

// ---- out[row] = final[row] / ||final[row]|| ----
__global__ void norm_kernel(const float* __restrict__ fin, float* __restrict__ out) {
  int row = blockIdx.x * 4 + (threadIdx.x >> 6);
  int lane = threadIdx.x & 63;
  const float* p = fin + (size_t)row * Dq;
  float4 v0 = *(const float4*)(p + lane * 8);
  float4 v1 = *(const float4*)(p + lane * 8 + 4);
  float ss = v0.x * v0.x + v0.y * v0.y + v0.z * v0.z + v0.w * v0.w +
             v1.x * v1.x + v1.y * v1.y + v1.z * v1.z + v1.w * v1.w;
#pragma unroll
  for (int o = 32; o; o >>= 1) ss += __shfl_xor(ss, o, 64);
  float rn = 1.f / sqrtf(ss);
  float* q = out + (size_t)row * Dq;
  v0.x *= rn; v0.y *= rn; v0.z *= rn; v0.w *= rn;
  v1.x *= rn; v1.y *= rn; v1.z *= rn; v1.w *= rn;
  *(float4*)(q + lane * 8) = v0;
  *(float4*)(q + lane * 8 + 4) = v1;
}

extern "C" void kernel_launch(void* const* d_in, const int* in_sizes, int n_in,
                              void* d_out, int out_size, void* d_ws, size_t ws_size,
                              hipStream_t stream) {
  const float* inp = (const float*)d_in[0];
  const float* inp_len = (const float*)d_in[1];
  const float* aspect = (const float*)d_in[2];
  const float* w1 = (const float*)d_in[3];
  const float* b1 = (const float*)d_in[4];
  const float* w2 = (const float*)d_in[5];
  const float* b2 = (const float*)d_in[6];
  float* out = (float*)d_out;

  char* W = (char*)d_ws;
  const size_t MB = 1ull << 20;
  unsigned short* inp_bf = (unsigned short*)(W + 0);        // 8 MB  [B][S][D]
  unsigned short* asp_bf = (unsigned short*)(W + 8 * MB);   // 8 MB  [B][S][D]
  unsigned short* inpT   = (unsigned short*)(W + 16 * MB);  // 8 MB  [B][D][S]
  unsigned short* att    = (unsigned short*)(W + 24 * MB);  // 16 MB [B][S][S] (bf16)
  float*          finalF = (float*)(W + 24 * MB);           // 16 MB (reuses att after GEMM2)
  float*          ffnF   = (float*)(W + 40 * MB);           // 16 MB [B*S][D]
  unsigned short* ffnBf  = (unsigned short*)(W + 56 * MB);  // 8 MB
  unsigned short* o1b    = (unsigned short*)(W + 64 * MB);  // 8 MB
  unsigned short* w1bf   = (unsigned short*)(W + 72 * MB);  // 512 KB
  unsigned short* w2bf   = (unsigned short*)(W + 72 * MB + 512 * 1024);
  float*          colsum = (float*)(W + 73 * MB);           // 16 KB
  float*          fac    = (float*)(W + 73 * MB + 64 * 1024);  // 32 KB

  // prep
  hipMemsetAsync(colsum, 0, Bq * Dq * sizeof(float), stream);
  prep_inp<<<dim3(32, 16, 8), dim3(32, 8), 0, stream>>>(inp, inp_bf, inpT, colsum);
  convert_bf<<<256, 256, 0, stream>>>(w1, w1bf);
  convert_bf<<<256, 256, 0, stream>>>(w2, w2bf);
  prep_asp<<<2048, 256, 0, stream>>>(aspect, colsum, inp_len, asp_bf, fac);

  // GEMM1: att_n[b][s][t] = (aspect[s]·inp[t]) * fac[b][s]   M=1024 N=1024 K=512
  {
    EpiArgs e{};
    e.fac = fac; e.outBf = att;
    gemm_bf16<1><<<dim3(16, 8, 8), 256, 0, stream>>>(
        asp_bf, inp_bf, 1024, 1024, 512,
        (long)Sq * Dq, (long)Sq * Dq, 0, (long)Sq * Sq, e);
  }
  // GEMM2: ffn_inp = att_n @ inp + (inp+aspect)*mask        M=1024 N=512 K=1024
  {
    EpiArgs e{};
    e.inp = inp; e.aspect = aspect; e.lenv = inp_len; e.outF = ffnF; e.outBf = ffnBf;
    gemm_bf16<2><<<dim3(8, 8, 8), 256, 0, stream>>>(
        att, inpT, 1024, 512, 1024,
        (long)Sq * Sq, (long)Dq * Sq, (long)Sq * Dq, (long)Sq * Dq, e);
  }
  // GEMM3: o1 = relu(ffn @ w1^T + b1)                        M=8192 N=512 K=512
  {
    EpiArgs e{};
    e.bias = b1; e.outBf = o1b;
    gemm_bf16<3><<<dim3(8, 64, 1), 256, 0, stream>>>(
        ffnBf, w1bf, 8192, 512, 512, 0, 0, 0, 0, e);
  }
  // GEMM4: final = 2*ffn + relu(o1 @ w2^T + b2)              M=8192 N=512 K=512
  {
    EpiArgs e{};
    e.bias = b2; e.resid = ffnF; e.outF = finalF;
    gemm_bf16<4><<<dim3(8, 64, 1), 256, 0, stream>>>(
        o1b, w2bf, 8192, 512, 512, 0, 0, 0, 0, e);
  }
  // normalize rows
  norm_kernel<<<2048, 256, 0, stream>>>(finalF, out);
}

// Round 3
// 224.679 us; speedup vs baseline: 1.0713x; 1.0144x over previous
//
#include <hip/hip_runtime.h>

#define Bq 8
#define Sq 1024
#define Dq 512

typedef __attribute__((ext_vector_type(8))) short bf16x8;
typedef __attribute__((ext_vector_type(4))) float f32x4;

__device__ __forceinline__ unsigned short f2bf(float f) {
  unsigned int u = __float_as_uint(f);
  return (unsigned short)((u + 0x7fffu + ((u >> 16) & 1u)) >> 16);
}

__device__ __forceinline__ void load_lds16(const unsigned short* g, unsigned short* l) {
  __builtin_amdgcn_global_load_lds(
      (const __attribute__((address_space(1))) unsigned int*)g,
      (__attribute__((address_space(3))) unsigned int*)l, 16, 0, 0);
}

// ---- both weights fp32 -> bf16 in one launch (512 blocks; 256 per weight) ----
__global__ void convert_w(const float* __restrict__ w1, unsigned short* __restrict__ w1b,
                          const float* __restrict__ w2, unsigned short* __restrict__ w2b) {
  int blk = blockIdx.x;
  const float* src = (blk < 256) ? w1 : w2;
  unsigned short* dst = (blk < 256) ? w1b : w2b;
  int i = ((blk & 255) * 256 + threadIdx.x) * 4;
  float4 v = *(const float4*)(src + i);
  ushort4 o;
  o.x = f2bf(v.x); o.y = f2bf(v.y); o.z = f2bf(v.z); o.w = f2bf(v.w);
  *(ushort4*)(dst + i) = o;
}

// ---- fused inp pass: bf16 cast + transpose + colsum partials ----
__global__ void prep_inp(const float* __restrict__ inp, unsigned short* __restrict__ inp_bf,
                         unsigned short* __restrict__ inpT, float* __restrict__ colsum) {
  __shared__ unsigned short tile[32][33];
  __shared__ float csum[8][33];
  int b = blockIdx.z;
  int t0 = blockIdx.x * 32, d0 = blockIdx.y * 32;
  int tx = threadIdx.x, ty = threadIdx.y;  // 32 x 8
  const float* src = inp + ((size_t)b * Sq + t0) * Dq + d0;
  unsigned short* dbf = inp_bf + ((size_t)b * Sq + t0) * Dq + d0;
  float part = 0.f;
#pragma unroll
  for (int i = 0; i < 4; ++i) {
    float v = src[(size_t)(ty + i * 8) * Dq + tx];
    unsigned short h = f2bf(v);
    tile[ty + i * 8][tx] = h;
    dbf[(size_t)(ty + i * 8) * Dq + tx] = h;
    part += v;
  }
  csum[ty][tx] = part;
  __syncthreads();
  unsigned short* dst = inpT + (size_t)b * Dq * Sq;
#pragma unroll
  for (int i = 0; i < 4; ++i)
    dst[(size_t)(d0 + ty + i * 8) * Sq + t0 + tx] = tile[tx][ty + i * 8];
  if (ty == 0) {
    float s = 0.f;
#pragma unroll
    for (int i = 0; i < 8; ++i) s += csum[i][tx];
    atomicAdd(&colsum[b * Dq + d0 + tx], s);
  }
}

// ---- fused aspect pass: bf16 cast + exact fp32 fac ----
__global__ void prep_asp(const float* __restrict__ aspect, const float* __restrict__ colsum,
                         const float* __restrict__ lenv, unsigned short* __restrict__ asp_bf,
                         float* __restrict__ fac) {
  int row = blockIdx.x * 4 + (threadIdx.x >> 6);
  int lane = threadIdx.x & 63;
  int b = row >> 10, s = row & 1023;
  const float* a = aspect + (size_t)row * Dq + lane * 8;
  const float* c = colsum + b * Dq + lane * 8;
  float4 a0 = *(const float4*)a, a1 = *(const float4*)(a + 4);
  float4 c0 = *(const float4*)c, c1 = *(const float4*)(c + 4);
  float sum = a0.x * c0.x + a0.y * c0.y + a0.z * c0.z + a0.w * c0.w +
              a1.x * c1.x + a1.y * c1.y + a1.z * c1.z + a1.w * c1.w;
  ushort4 o0; o0.x = f2bf(a0.x); o0.y = f2bf(a0.y); o0.z = f2bf(a0.z); o0.w = f2bf(a0.w);
  ushort4 o1; o1.x = f2bf(a1.x); o1.y = f2bf(a1.y); o1.z = f2bf(a1.z); o1.w = f2bf(a1.w);
  unsigned short* dst = asp_bf + (size_t)row * Dq + lane * 8;
  *(ushort4*)dst = o0;
  *(ushort4*)(dst + 4) = o1;
#pragma unroll
  for (int o = 32; o; o >>= 1) sum += __shfl_xor(sum, o, 64);
  if (lane == 0) {
    float len = lenv[b];
    float scale = sqrtf(len);
    float f = 0.f;
    if (s < (int)len) f = 1.f / (scale * (sum / scale + 1e-4f));
    fac[row] = f;
  }
}

// ---- 64x64x(BK=64) bf16 MFMA GEMM: C[M][N] = A[M][K]*B[N][K]^T ----
// 4 waves each 32x32 (2x2 frags), global_load_lds staging into frag-major LDS
// (granule = c*256 + lq*64 + row). MODE 0: x=batch (XCD-pin batch), MODE 1:
// x=bm (XCD-pin A-stripe), b=0.
struct EpiArgs {
  const float* fac;
  const float* inp;
  const float* aspect;
  const float* lenv;
  const float* bias;
  const float* resid;
  float* outF;
  unsigned short* outBf;
};

template <int EPI, int MODE>
__global__ __launch_bounds__(256, 6) void gemm_bf16(
    const unsigned short* __restrict__ Ag, const unsigned short* __restrict__ Bg,
    int M, int N, int K, long strideA, long strideB, long strideOF, long strideOBf,
    EpiArgs e) {
  __shared__ unsigned short sA[64 * 64];  // 8 KB
  __shared__ unsigned short sB[64 * 64];  // 8 KB
  int b, bm, bn;
  if (MODE == 0) { b = blockIdx.x; bm = blockIdx.y; bn = blockIdx.z; }
  else           { b = 0; bm = blockIdx.x; bn = blockIdx.y; }
  const unsigned short* Ab = Ag + (size_t)b * strideA + (size_t)bm * 64 * K;
  const unsigned short* Bb = Bg + (size_t)b * strideB + (size_t)bn * 64 * K;
  int tid = threadIdx.x;
  int lane = tid & 63, wave = tid >> 6;
  int wm = (wave >> 1) * 32, wn = (wave & 1) * 32;
  int lr = lane & 15, lq = lane >> 4;

  // staging: thread tid owns granules tid (c=0) and tid+256 (c=1)
  int srow = tid & 63, slq = (tid >> 6) & 3;
  const unsigned short* gA = Ab + (size_t)srow * K + slq * 8;
  const unsigned short* gB = Bb + (size_t)srow * K + slq * 8;
  unsigned short* lA0 = &sA[(size_t)tid * 8];
  unsigned short* lA1 = &sA[(size_t)(tid + 256) * 8];
  unsigned short* lB0 = &sB[(size_t)tid * 8];
  unsigned short* lB1 = &sB[(size_t)(tid + 256) * 8];

  f32x4 acc[2][2] = {};

  for (int k0 = 0; k0 < K; k0 += 64) {
    load_lds16(gA + k0, lA0);
    load_lds16(gA + k0 + 32, lA1);
    load_lds16(gB + k0, lB0);
    load_lds16(gB + k0 + 32, lB1);
    __syncthreads();
#pragma unroll
    for (int c = 0; c < 2; ++c) {
      bf16x8 a0 = *(const bf16x8*)&sA[(size_t)(c * 256 + lq * 64 + wm + lr) * 8];
      bf16x8 a1 = *(const bf16x8*)&sA[(size_t)(c * 256 + lq * 64 + wm + 16 + lr) * 8];
      bf16x8 b0 = *(const bf16x8*)&sB[(size_t)(c * 256 + lq * 64 + wn + lr) * 8];
      bf16x8 b1 = *(const bf16x8*)&sB[(size_t)(c * 256 + lq * 64 + wn + 16 + lr) * 8];
      acc[0][0] = __builtin_amdgcn_mfma_f32_16x16x32_bf16(a0, b0, acc[0][0], 0, 0, 0);
      acc[0][1] = __builtin_amdgcn_mfma_f32_16x16x32_bf16(a0, b1, acc[0][1], 0, 0, 0);
      acc[1][0] = __builtin_amdgcn_mfma_f32_16x16x32_bf16(a1, b0, acc[1][0], 0, 0, 0);
      acc[1][1] = __builtin_amdgcn_mfma_f32_16x16x32_bf16(a1, b1, acc[1][1], 0, 0, 0);
    }
    __syncthreads();
  }

#pragma unroll
  for (int mi = 0; mi < 2; ++mi) {
#pragma unroll
    for (int ni = 0; ni < 2; ++ni) {
#pragma unroll
      for (int i = 0; i < 4; ++i) {
        int r = bm * 64 + wm + mi * 16 + lq * 4 + i;
        int cc = bn * 64 + wn + ni * 16 + lr;
        float v = acc[mi][ni][i];
        if (EPI == 1) {
          float f = e.fac[(size_t)b * M + r];
          e.outBf[(size_t)b * strideOBf + (size_t)r * N + cc] = f2bf(v * f);
        } else if (EPI == 2) {
          int len = (int)e.lenv[b];
          size_t idx = (size_t)b * ((size_t)Sq * Dq) + (size_t)r * Dq + cc;
          float add = (r < len) ? (e.inp[idx] + e.aspect[idx]) : 0.f;
          float o = v + add;
          e.outF[(size_t)b * strideOF + (size_t)r * N + cc] = o;
          e.outBf[(size_t)b * strideOBf + (size_t)r * N + cc] = f2bf(o);
        } else if (EPI == 3) {
          float o = fmaxf(v + e.bias[cc], 0.f);
          e.outBf[(size_t)r * N + cc] = f2bf(o);
        } else {
          float o = fmaxf(v + e.bias[cc], 0.f);
          size_t idx = (size_t)r * N + cc;
          e.outF[idx] = 2.f * e.resid[idx] + o;
        }
      }
    }
  }
}

// ---- out[row] = final[row] / ||final[row]|| ----
__global__ void norm_kernel(const float* __restrict__ fin, float* __restrict__ out) {
  int row = blockIdx.x * 4 + (threadIdx.x >> 6);
  int lane = threadIdx.x & 63;
  const float* p = fin + (size_t)row * Dq;
  float4 v0 = *(const float4*)(p + lane * 8);
  float4 v1 = *(const float4*)(p + lane * 8 + 4);
  float ss = v0.x * v0.x + v0.y * v0.y + v0.z * v0.z + v0.w * v0.w +
             v1.x * v1.x + v1.y * v1.y + v1.z * v1.z + v1.w * v1.w;
#pragma unroll
  for (int o = 32; o; o >>= 1) ss += __shfl_xor(ss, o, 64);
  float rn = 1.f / sqrtf(ss);
  float* q = out + (size_t)row * Dq;
  v0.x *= rn; v0.y *= rn; v0.z *= rn; v0.w *= rn;
  v1.x *= rn; v1.y *= rn; v1.z *= rn; v1.w *= rn;
  *(float4*)(q + lane * 8) = v0;
  *(float4*)(q + lane * 8 + 4) = v1;
}

extern "C" void kernel_launch(void* const* d_in, const int* in_sizes, int n_in,
                              void* d_out, int out_size, void* d_ws, size_t ws_size,
                              hipStream_t stream) {
  const float* inp = (const float*)d_in[0];
  const float* inp_len = (const float*)d_in[1];
  const float* aspect = (const float*)d_in[2];
  const float* w1 = (const float*)d_in[3];
  const float* b1 = (const float*)d_in[4];
  const float* w2 = (const float*)d_in[5];
  const float* b2 = (const float*)d_in[6];
  float* out = (float*)d_out;

  char* W = (char*)d_ws;
  const size_t MB = 1ull << 20;
  unsigned short* inp_bf = (unsigned short*)(W + 0);        // 8 MB  [B][S][D]
  unsigned short* asp_bf = (unsigned short*)(W + 8 * MB);   // 8 MB  [B][S][D]
  unsigned short* inpT   = (unsigned short*)(W + 16 * MB);  // 8 MB  [B][D][S]
  unsigned short* att    = (unsigned short*)(W + 24 * MB);  // 16 MB [B][S][S] (bf16)
  float*          finalF = (float*)(W + 24 * MB);           // 16 MB (reuses att after GEMM2)
  float*          ffnF   = (float*)(W + 40 * MB);           // 16 MB [B*S][D]
  unsigned short* ffnBf  = (unsigned short*)(W + 56 * MB);  // 8 MB
  unsigned short* o1b    = (unsigned short*)(W + 64 * MB);  // 8 MB
  unsigned short* w1bf   = (unsigned short*)(W + 72 * MB);  // 512 KB
  unsigned short* w2bf   = (unsigned short*)(W + 72 * MB + 512 * 1024);
  float*          colsum = (float*)(W + 73 * MB);           // 16 KB
  float*          fac    = (float*)(W + 73 * MB + 64 * 1024);  // 32 KB

  // prep
  hipMemsetAsync(colsum, 0, Bq * Dq * sizeof(float), stream);
  prep_inp<<<dim3(32, 16, 8), dim3(32, 8), 0, stream>>>(inp, inp_bf, inpT, colsum);
  convert_w<<<512, 256, 0, stream>>>(w1, w1bf, w2, w2bf);
  prep_asp<<<2048, 256, 0, stream>>>(aspect, colsum, inp_len, asp_bf, fac);

  // GEMM1: att_n = (aspect . inp) * fac   M=1024 N=1024 K=512  (x=batch)
  {
    EpiArgs e{};
    e.fac = fac; e.outBf = att;
    gemm_bf16<1, 0><<<dim3(8, 16, 16), 256, 0, stream>>>(
        asp_bf, inp_bf, 1024, 1024, 512,
        (long)Sq * Dq, (long)Sq * Dq, 0, (long)Sq * Sq, e);
  }
  // GEMM2: ffn_inp = att_n @ inp + (inp+aspect)*mask   M=1024 N=512 K=1024
  {
    EpiArgs e{};
    e.inp = inp; e.aspect = aspect; e.lenv = inp_len; e.outF = ffnF; e.outBf = ffnBf;
    gemm_bf16<2, 0><<<dim3(8, 16, 8), 256, 0, stream>>>(
        att, inpT, 1024, 512, 1024,
        (long)Sq * Sq, (long)Dq * Sq, (long)Sq * Dq, (long)Sq * Dq, e);
  }
  // GEMM3: o1 = relu(ffn @ w1^T + b1)   M=8192 N=512 K=512  (x=bm)
  {
    EpiArgs e{};
    e.bias = b1; e.outBf = o1b;
    gemm_bf16<3, 1><<<dim3(128, 8), 256, 0, stream>>>(
        ffnBf, w1bf, 8192, 512, 512, 0, 0, 0, 0, e);
  }
  // GEMM4: final = 2*ffn + relu(o1 @ w2^T + b2)   M=8192 N=512 K=512
  {
    EpiArgs e{};
    e.bias = b2; e.resid = ffnF; e.outF = finalF;
    gemm_bf16<4, 1><<<dim3(128, 8), 256, 0, stream>>>(
        o1b, w2bf, 8192, 512, 512, 0, 0, 0, 0, e);
  }
  // normalize rows
  norm_kernel<<<2048, 256, 0, stream>>>(finalF, out);
}

// Round 4
// 190.997 us; speedup vs baseline: 1.2603x; 1.1764x over previous
//
#include <hip/hip_runtime.h>

#define Bq 8
#define Sq 1024
#define Dq 512

typedef __attribute__((ext_vector_type(8))) short bf16x8;
typedef __attribute__((ext_vector_type(4))) float f32x4;

__device__ __forceinline__ unsigned short f2bf(float f) {
  unsigned int u = __float_as_uint(f);
  return (unsigned short)((u + 0x7fffu + ((u >> 16) & 1u)) >> 16);
}

__device__ __forceinline__ void load_lds16(const unsigned short* g, unsigned short* l) {
  __builtin_amdgcn_global_load_lds(
      (const __attribute__((address_space(1))) unsigned int*)g,
      (__attribute__((address_space(3))) unsigned int*)l, 16, 0, 0);
}

// ---- both weights fp32 -> bf16 in one launch ----
__global__ void convert_w(const float* __restrict__ w1, unsigned short* __restrict__ w1b,
                          const float* __restrict__ w2, unsigned short* __restrict__ w2b) {
  int blk = blockIdx.x;
  const float* src = (blk < 256) ? w1 : w2;
  unsigned short* dst = (blk < 256) ? w1b : w2b;
  int i = ((blk & 255) * 256 + threadIdx.x) * 4;
  float4 v = *(const float4*)(src + i);
  ushort4 o;
  o.x = f2bf(v.x); o.y = f2bf(v.y); o.z = f2bf(v.z); o.w = f2bf(v.w);
  *(ushort4*)(dst + i) = o;
}

// ---- fused inp pass: bf16 cast + transpose + colsum partials ----
__global__ void prep_inp(const float* __restrict__ inp, unsigned short* __restrict__ inp_bf,
                         unsigned short* __restrict__ inpT, float* __restrict__ colsum) {
  __shared__ unsigned short tile[32][33];
  __shared__ float csum[8][33];
  int b = blockIdx.z;
  int t0 = blockIdx.x * 32, d0 = blockIdx.y * 32;
  int tx = threadIdx.x, ty = threadIdx.y;  // 32 x 8
  const float* src = inp + ((size_t)b * Sq + t0) * Dq + d0;
  unsigned short* dbf = inp_bf + ((size_t)b * Sq + t0) * Dq + d0;
  float part = 0.f;
#pragma unroll
  for (int i = 0; i < 4; ++i) {
    float v = src[(size_t)(ty + i * 8) * Dq + tx];
    unsigned short h = f2bf(v);
    tile[ty + i * 8][tx] = h;
    dbf[(size_t)(ty + i * 8) * Dq + tx] = h;
    part += v;
  }
  csum[ty][tx] = part;
  __syncthreads();
  unsigned short* dst = inpT + (size_t)b * Dq * Sq;
#pragma unroll
  for (int i = 0; i < 4; ++i)
    dst[(size_t)(d0 + ty + i * 8) * Sq + t0 + tx] = tile[tx][ty + i * 8];
  if (ty == 0) {
    float s = 0.f;
#pragma unroll
    for (int i = 0; i < 8; ++i) s += csum[i][tx];
    atomicAdd(&colsum[b * Dq + d0 + tx], s);
  }
}

// ---- fused aspect pass: bf16 cast + exact fp32 fac ----
__global__ void prep_asp(const float* __restrict__ aspect, const float* __restrict__ colsum,
                         const float* __restrict__ lenv, unsigned short* __restrict__ asp_bf,
                         float* __restrict__ fac) {
  int row = blockIdx.x * 4 + (threadIdx.x >> 6);
  int lane = threadIdx.x & 63;
  int b = row >> 10, s = row & 1023;
  const float* a = aspect + (size_t)row * Dq + lane * 8;
  const float* c = colsum + b * Dq + lane * 8;
  float4 a0 = *(const float4*)a, a1 = *(const float4*)(a + 4);
  float4 c0 = *(const float4*)c, c1 = *(const float4*)(c + 4);
  float sum = a0.x * c0.x + a0.y * c0.y + a0.z * c0.z + a0.w * c0.w +
              a1.x * c1.x + a1.y * c1.y + a1.z * c1.z + a1.w * c1.w;
  ushort4 o0; o0.x = f2bf(a0.x); o0.y = f2bf(a0.y); o0.z = f2bf(a0.z); o0.w = f2bf(a0.w);
  ushort4 o1; o1.x = f2bf(a1.x); o1.y = f2bf(a1.y); o1.z = f2bf(a1.z); o1.w = f2bf(a1.w);
  unsigned short* dst = asp_bf + (size_t)row * Dq + lane * 8;
  *(ushort4*)dst = o0;
  *(ushort4*)(dst + 4) = o1;
#pragma unroll
  for (int o = 32; o; o >>= 1) sum += __shfl_xor(sum, o, 64);
  if (lane == 0) {
    float len = lenv[b];
    float scale = sqrtf(len);
    float f = 0.f;
    if (s < (int)len) f = 1.f / (scale * (sum / scale + 1e-4f));
    fac[row] = f;
  }
}

// ---- 128x128x(BK=128) bf16 MFMA GEMM: C = A[M][K] * B[N][K]^T ----
// Coalesced global_load_lds: each instr = 64 lanes x 16B over CONTIGUOUS 1KB
// (8 full cache lines) -> 8x fewer memory requests than strided gather.
// LDS is XOR-swizzled row-major: granule (row r, kchunk c) lives at slot
// r*16 + (c ^ (r&7)); staging lane l of instr j loads mem chunk
// (l&15)^((rg+l>>4)&7) so the lane-linear LDS dest realizes that swizzle.
// ds_read_b128 frag reads then hit 2-way banks (free).
struct EpiArgs {
  const float* fac;
  const float* inp;
  const float* aspect;
  const float* lenv;
  const float* bias;
  const float* resid;
  float* outF;
  unsigned short* outBf;
};

template <int EPI, int MODE>
__global__ __launch_bounds__(256, 2) void gemm_bf16(
    const unsigned short* __restrict__ Ag, const unsigned short* __restrict__ Bg,
    int M, int N, int K, long strideA, long strideB, long strideOF, long strideOBf,
    EpiArgs e) {
  __shared__ unsigned short sA[128 * 128];  // 32 KB
  __shared__ unsigned short sB[128 * 128];  // 32 KB
  int b, bm, bn;
  if (MODE == 0) { b = blockIdx.x; bm = blockIdx.y; bn = blockIdx.z; }
  else           { b = 0; bm = blockIdx.x; bn = blockIdx.y; }
  const unsigned short* Ab = Ag + (size_t)b * strideA + (size_t)bm * 128 * K;
  const unsigned short* Bb = Bg + (size_t)b * strideB + (size_t)bn * 128 * K;
  int tid = threadIdx.x;
  int lane = tid & 63, wave = tid >> 6;
  int wm = (wave >> 1) * 64, wn = (wave & 1) * 64;
  int lr = lane & 15, lq = lane >> 4;
  int x = lr & 7;

  // staging: instr j of this wave covers rows rg..rg+3 (rg=(wave*8+j)*4),
  // lane l -> row rg + (l>>4), mem kchunk (l&15)^xj, xj=(j&1)*4 + (l>>4)
  int l4 = lane >> 4, g16 = lane & 15;
  const unsigned short* a_even = Ab + (size_t)l4 * K + ((g16 ^ l4) * 8);
  const unsigned short* a_odd  = Ab + (size_t)l4 * K + ((g16 ^ (4 + l4)) * 8);
  const unsigned short* b_even = Bb + (size_t)l4 * K + ((g16 ^ l4) * 8);
  const unsigned short* b_odd  = Bb + (size_t)l4 * K + ((g16 ^ (4 + l4)) * 8);

  f32x4 acc[4][4] = {};

  for (int k0 = 0; k0 < K; k0 += 128) {
#pragma unroll
    for (int j = 0; j < 8; ++j) {
      int rg = (wave * 8 + j) * 4;
      const unsigned short* sa = ((j & 1) ? a_odd : a_even) + (size_t)rg * K + k0;
      const unsigned short* sb = ((j & 1) ? b_odd : b_even) + (size_t)rg * K + k0;
      unsigned short* da = &sA[rg * 128 + lane * 8];
      unsigned short* db = &sB[rg * 128 + lane * 8];
      load_lds16(sa, da);
      load_lds16(sb, db);
    }
    __syncthreads();
#pragma unroll
    for (int h = 0; h < 4; ++h) {
      int co = ((h * 4 + lq) ^ x) * 8;
      bf16x8 af[4], bv[4];
#pragma unroll
      for (int mi = 0; mi < 4; ++mi)
        af[mi] = *(const bf16x8*)&sA[(wm + mi * 16 + lr) * 128 + co];
#pragma unroll
      for (int ni = 0; ni < 4; ++ni)
        bv[ni] = *(const bf16x8*)&sB[(wn + ni * 16 + lr) * 128 + co];
#pragma unroll
      for (int mi = 0; mi < 4; ++mi)
#pragma unroll
        for (int ni = 0; ni < 4; ++ni)
          acc[mi][ni] = __builtin_amdgcn_mfma_f32_16x16x32_bf16(af[mi], bv[ni], acc[mi][ni], 0, 0, 0);
    }
    __syncthreads();
  }

#pragma unroll
  for (int mi = 0; mi < 4; ++mi) {
#pragma unroll
    for (int ni = 0; ni < 4; ++ni) {
#pragma unroll
      for (int i = 0; i < 4; ++i) {
        int r = bm * 128 + wm + mi * 16 + lq * 4 + i;
        int cc = bn * 128 + wn + ni * 16 + lr;
        float v = acc[mi][ni][i];
        if (EPI == 1) {
          float f = e.fac[(size_t)b * M + r];
          e.outBf[(size_t)b * strideOBf + (size_t)r * N + cc] = f2bf(v * f);
        } else if (EPI == 2) {
          int len = (int)e.lenv[b];
          size_t idx = (size_t)b * ((size_t)Sq * Dq) + (size_t)r * Dq + cc;
          float add = (r < len) ? (e.inp[idx] + e.aspect[idx]) : 0.f;
          float o = v + add;
          e.outF[(size_t)b * strideOF + (size_t)r * N + cc] = o;
          e.outBf[(size_t)b * strideOBf + (size_t)r * N + cc] = f2bf(o);
        } else if (EPI == 3) {
          float o = fmaxf(v + e.bias[cc], 0.f);
          e.outBf[(size_t)r * N + cc] = f2bf(o);
        } else {
          float o = fmaxf(v + e.bias[cc], 0.f);
          size_t idx = (size_t)r * N + cc;
          e.outF[idx] = 2.f * e.resid[idx] + o;
        }
      }
    }
  }
}

// ---- out[row] = final[row] / ||final[row]|| ----
__global__ void norm_kernel(const float* __restrict__ fin, float* __restrict__ out) {
  int row = blockIdx.x * 4 + (threadIdx.x >> 6);
  int lane = threadIdx.x & 63;
  const float* p = fin + (size_t)row * Dq;
  float4 v0 = *(const float4*)(p + lane * 8);
  float4 v1 = *(const float4*)(p + lane * 8 + 4);
  float ss = v0.x * v0.x + v0.y * v0.y + v0.z * v0.z + v0.w * v0.w +
             v1.x * v1.x + v1.y * v1.y + v1.z * v1.z + v1.w * v1.w;
#pragma unroll
  for (int o = 32; o; o >>= 1) ss += __shfl_xor(ss, o, 64);
  float rn = 1.f / sqrtf(ss);
  float* q = out + (size_t)row * Dq;
  v0.x *= rn; v0.y *= rn; v0.z *= rn; v0.w *= rn;
  v1.x *= rn; v1.y *= rn; v1.z *= rn; v1.w *= rn;
  *(float4*)(q + lane * 8) = v0;
  *(float4*)(q + lane * 8 + 4) = v1;
}

extern "C" void kernel_launch(void* const* d_in, const int* in_sizes, int n_in,
                              void* d_out, int out_size, void* d_ws, size_t ws_size,
                              hipStream_t stream) {
  const float* inp = (const float*)d_in[0];
  const float* inp_len = (const float*)d_in[1];
  const float* aspect = (const float*)d_in[2];
  const float* w1 = (const float*)d_in[3];
  const float* b1 = (const float*)d_in[4];
  const float* w2 = (const float*)d_in[5];
  const float* b2 = (const float*)d_in[6];
  float* out = (float*)d_out;

  char* W = (char*)d_ws;
  const size_t MB = 1ull << 20;
  unsigned short* inp_bf = (unsigned short*)(W + 0);        // 8 MB  [B][S][D]
  unsigned short* asp_bf = (unsigned short*)(W + 8 * MB);   // 8 MB  [B][S][D]
  unsigned short* inpT   = (unsigned short*)(W + 16 * MB);  // 8 MB  [B][D][S]
  unsigned short* att    = (unsigned short*)(W + 24 * MB);  // 16 MB [B][S][S] (bf16)
  float*          finalF = (float*)(W + 24 * MB);           // 16 MB (reuses att after GEMM2)
  float*          ffnF   = (float*)(W + 40 * MB);           // 16 MB [B*S][D]
  unsigned short* ffnBf  = (unsigned short*)(W + 56 * MB);  // 8 MB
  unsigned short* o1b    = (unsigned short*)(W + 64 * MB);  // 8 MB
  unsigned short* w1bf   = (unsigned short*)(W + 72 * MB);  // 512 KB
  unsigned short* w2bf   = (unsigned short*)(W + 72 * MB + 512 * 1024);
  float*          colsum = (float*)(W + 73 * MB);           // 16 KB
  float*          fac    = (float*)(W + 73 * MB + 64 * 1024);  // 32 KB

  // prep
  hipMemsetAsync(colsum, 0, Bq * Dq * sizeof(float), stream);
  prep_inp<<<dim3(32, 16, 8), dim3(32, 8), 0, stream>>>(inp, inp_bf, inpT, colsum);
  convert_w<<<512, 256, 0, stream>>>(w1, w1bf, w2, w2bf);
  prep_asp<<<2048, 256, 0, stream>>>(aspect, colsum, inp_len, asp_bf, fac);

  // GEMM1: att_n = (aspect . inp) * fac   M=1024 N=1024 K=512  (x=batch -> XCD pin)
  {
    EpiArgs e{};
    e.fac = fac; e.outBf = att;
    gemm_bf16<1, 0><<<dim3(8, 8, 8), 256, 0, stream>>>(
        asp_bf, inp_bf, 1024, 1024, 512,
        (long)Sq * Dq, (long)Sq * Dq, 0, (long)Sq * Sq, e);
  }
  // GEMM2: ffn_inp = att_n @ inp + (inp+aspect)*mask   M=1024 N=512 K=1024
  {
    EpiArgs e{};
    e.inp = inp; e.aspect = aspect; e.lenv = inp_len; e.outF = ffnF; e.outBf = ffnBf;
    gemm_bf16<2, 0><<<dim3(8, 8, 4), 256, 0, stream>>>(
        att, inpT, 1024, 512, 1024,
        (long)Sq * Sq, (long)Dq * Sq, (long)Sq * Dq, (long)Sq * Dq, e);
  }
  // GEMM3: o1 = relu(ffn @ w1^T + b1)   M=8192 N=512 K=512  (x=bm -> XCD pin)
  {
    EpiArgs e{};
    e.bias = b1; e.outBf = o1b;
    gemm_bf16<3, 1><<<dim3(64, 4), 256, 0, stream>>>(
        ffnBf, w1bf, 8192, 512, 512, 0, 0, 0, 0, e);
  }
  // GEMM4: final = 2*ffn + relu(o1 @ w2^T + b2)   M=8192 N=512 K=512
  {
    EpiArgs e{};
    e.bias = b2; e.resid = ffnF; e.outF = finalF;
    gemm_bf16<4, 1><<<dim3(64, 4), 256, 0, stream>>>(
        o1b, w2bf, 8192, 512, 512, 0, 0, 0, 0, e);
  }
  // normalize rows
  norm_kernel<<<2048, 256, 0, stream>>>(finalF, out);
}

// Round 5
// 179.562 us; speedup vs baseline: 1.3405x; 1.0637x over previous
//
#include <hip/hip_runtime.h>

#define Bq 8
#define Sq 1024
#define Dq 512

typedef __attribute__((ext_vector_type(8))) short bf16x8;
typedef __attribute__((ext_vector_type(4))) float f32x4;

__device__ __forceinline__ unsigned short f2bf(float f) {
  unsigned int u = __float_as_uint(f);
  return (unsigned short)((u + 0x7fffu + ((u >> 16) & 1u)) >> 16);
}

__device__ __forceinline__ void load_lds16(const unsigned short* g, unsigned short* l) {
  __builtin_amdgcn_global_load_lds(
      (const __attribute__((address_space(1))) unsigned int*)g,
      (__attribute__((address_space(3))) unsigned int*)l, 16, 0, 0);
}

// ---- both weights fp32 -> bf16 in one launch ----
__global__ void convert_w(const float* __restrict__ w1, unsigned short* __restrict__ w1b,
                          const float* __restrict__ w2, unsigned short* __restrict__ w2b) {
  int blk = blockIdx.x;
  const float* src = (blk < 256) ? w1 : w2;
  unsigned short* dst = (blk < 256) ? w1b : w2b;
  int i = ((blk & 255) * 256 + threadIdx.x) * 4;
  float4 v = *(const float4*)(src + i);
  ushort4 o;
  o.x = f2bf(v.x); o.y = f2bf(v.y); o.z = f2bf(v.z); o.w = f2bf(v.w);
  *(ushort4*)(dst + i) = o;
}

// ---- fused inp pass: bf16 cast + transpose + colsum; x=batch so inpT[b],
// inp_bf[b] land in XCD b's L2 (same pin as the GEMMs that read them) ----
__global__ void prep_inp(const float* __restrict__ inp, unsigned short* __restrict__ inp_bf,
                         unsigned short* __restrict__ inpT, float* __restrict__ colsum) {
  __shared__ unsigned short tile[32][33];
  __shared__ float csum[8][33];
  int b = blockIdx.x;
  int t0 = blockIdx.y * 32, d0 = blockIdx.z * 32;
  int tx = threadIdx.x, ty = threadIdx.y;  // 32 x 8
  const float* src = inp + ((size_t)b * Sq + t0) * Dq + d0;
  unsigned short* dbf = inp_bf + ((size_t)b * Sq + t0) * Dq + d0;
  float part = 0.f;
#pragma unroll
  for (int i = 0; i < 4; ++i) {
    float v = src[(size_t)(ty + i * 8) * Dq + tx];
    unsigned short h = f2bf(v);
    tile[ty + i * 8][tx] = h;
    dbf[(size_t)(ty + i * 8) * Dq + tx] = h;
    part += v;
  }
  csum[ty][tx] = part;
  __syncthreads();
  unsigned short* dst = inpT + (size_t)b * Dq * Sq;
#pragma unroll
  for (int i = 0; i < 4; ++i)
    dst[(size_t)(d0 + ty + i * 8) * Sq + t0 + tx] = tile[tx][ty + i * 8];
  if (ty == 0) {
    float s = 0.f;
#pragma unroll
    for (int i = 0; i < 8; ++i) s += csum[i][tx];
    atomicAdd(&colsum[b * Dq + d0 + tx], s);
  }
}

// ---- fused aspect pass: bf16 cast + exact fp32 fac ----
__global__ void prep_asp(const float* __restrict__ aspect, const float* __restrict__ colsum,
                         const float* __restrict__ lenv, unsigned short* __restrict__ asp_bf,
                         float* __restrict__ fac) {
  int row = blockIdx.x * 4 + (threadIdx.x >> 6);
  int lane = threadIdx.x & 63;
  int b = row >> 10, s = row & 1023;
  const float* a = aspect + (size_t)row * Dq + lane * 8;
  const float* c = colsum + b * Dq + lane * 8;
  float4 a0 = *(const float4*)a, a1 = *(const float4*)(a + 4);
  float4 c0 = *(const float4*)c, c1 = *(const float4*)(c + 4);
  float sum = a0.x * c0.x + a0.y * c0.y + a0.z * c0.z + a0.w * c0.w +
              a1.x * c1.x + a1.y * c1.y + a1.z * c1.z + a1.w * c1.w;
  ushort4 o0; o0.x = f2bf(a0.x); o0.y = f2bf(a0.y); o0.z = f2bf(a0.z); o0.w = f2bf(a0.w);
  ushort4 o1; o1.x = f2bf(a1.x); o1.y = f2bf(a1.y); o1.z = f2bf(a1.z); o1.w = f2bf(a1.w);
  unsigned short* dst = asp_bf + (size_t)row * Dq + lane * 8;
  *(ushort4*)dst = o0;
  *(ushort4*)(dst + 4) = o1;
#pragma unroll
  for (int o = 32; o; o >>= 1) sum += __shfl_xor(sum, o, 64);
  if (lane == 0) {
    float len = lenv[b];
    float scale = sqrtf(len);
    float f = 0.f;
    if (s < (int)len) f = 1.f / (scale * (sum / scale + 1e-4f));
    fac[row] = f;
  }
}

// ---- 128x64 tile, BK=64, DOUBLE-BUFFERED bf16 MFMA GEMM: C = A*B^T ----
// Coalesced global_load_lds (each instr = 8 full 128B lines), XOR-swizzled
// LDS (granule (row,c) at row*8 + (c^(row&7))); frag ds_read_b128 hits the
// uniform 8-lane/bank-group structural floor. K-loop: barrier drains buf
// cur (its loads overlapped the PREVIOUS compute), issue buf cur^1, compute
// cur -> memory and MFMA overlap across iterations.
struct EpiArgs {
  const float* fac;
  const float* inp;
  const float* aspect;
  const float* lenv;
  const float* bias;
  const float* resid;
  float* outF;
  unsigned short* outBf;
};

template <int EPI, int MODE>
__global__ __launch_bounds__(256, 3) void gemm_bf16(
    const unsigned short* __restrict__ Ag, const unsigned short* __restrict__ Bg,
    int M, int N, int K, long strideA, long strideB, long strideOF, long strideOBf,
    EpiArgs e) {
  __shared__ unsigned short sA[2][128 * 64];  // 2 x 16 KB
  __shared__ unsigned short sB[2][64 * 64];   // 2 x 8 KB
  int b, bm, bn;
  if (MODE == 0) { b = blockIdx.x; bm = blockIdx.y; bn = blockIdx.z; }
  else           { b = 0; bm = blockIdx.x; bn = blockIdx.y; }
  const unsigned short* Ab = Ag + (size_t)b * strideA + (size_t)bm * 128 * K;
  const unsigned short* Bb = Bg + (size_t)b * strideB + (size_t)bn * 64 * K;
  int tid = threadIdx.x;
  int lane = tid & 63, wave = tid >> 6;
  int wm = wave * 32;
  int lr = lane & 15, lq = lane >> 4;
  int l3 = lane >> 3, l7 = lane & 7;

  // staging: instr covers 8 rows x 128B; lane l -> row +(l>>3), chunk (l&7)^(l>>3)
  const unsigned short* gA = Ab + (size_t)l3 * K + (l7 ^ l3) * 8 + (size_t)wave * 32 * K;
  const unsigned short* gB = Bb + (size_t)l3 * K + (l7 ^ l3) * 8 + (size_t)wave * 16 * K;
  unsigned short* dA = &sA[0][wave * 2048 + lane * 8];
  unsigned short* dB = &sB[0][wave * 1024 + lane * 8];

  f32x4 acc[2][4] = {};

  auto issue = [&](int buf, int k0) {
#pragma unroll
    for (int j = 0; j < 4; ++j)
      load_lds16(gA + (size_t)j * 8 * K + k0, dA + buf * 8192 + j * 512);
#pragma unroll
    for (int j = 0; j < 2; ++j)
      load_lds16(gB + (size_t)j * 8 * K + k0, dB + buf * 4096 + j * 512);
  };

  int nk = K >> 6;
  issue(0, 0);
  for (int it = 0; it < nk; ++it) {
    int cur = it & 1;
    __syncthreads();
    if (it + 1 < nk) issue(cur ^ 1, (it + 1) << 6);
#pragma unroll
    for (int w2 = 0; w2 < 2; ++w2) {
      int xo = ((w2 * 4 + lq) ^ (lr & 7)) * 8;
      bf16x8 af0 = *(const bf16x8*)&sA[cur][(wm + lr) * 64 + xo];
      bf16x8 af1 = *(const bf16x8*)&sA[cur][(wm + 16 + lr) * 64 + xo];
      bf16x8 bv[4];
#pragma unroll
      for (int ni = 0; ni < 4; ++ni)
        bv[ni] = *(const bf16x8*)&sB[cur][(ni * 16 + lr) * 64 + xo];
#pragma unroll
      for (int ni = 0; ni < 4; ++ni) {
        acc[0][ni] = __builtin_amdgcn_mfma_f32_16x16x32_bf16(af0, bv[ni], acc[0][ni], 0, 0, 0);
        acc[1][ni] = __builtin_amdgcn_mfma_f32_16x16x32_bf16(af1, bv[ni], acc[1][ni], 0, 0, 0);
      }
    }
  }

#pragma unroll
  for (int mi = 0; mi < 2; ++mi) {
#pragma unroll
    for (int ni = 0; ni < 4; ++ni) {
#pragma unroll
      for (int i = 0; i < 4; ++i) {
        int r = bm * 128 + wm + mi * 16 + lq * 4 + i;
        int cc = bn * 64 + ni * 16 + lr;
        float v = acc[mi][ni][i];
        if (EPI == 1) {
          float f = e.fac[(size_t)b * M + r];
          e.outBf[(size_t)b * strideOBf + (size_t)r * N + cc] = f2bf(v * f);
        } else if (EPI == 2) {
          int len = (int)e.lenv[b];
          size_t idx = (size_t)b * ((size_t)Sq * Dq) + (size_t)r * Dq + cc;
          float add = (r < len) ? (e.inp[idx] + e.aspect[idx]) : 0.f;
          float o = v + add;
          e.outF[(size_t)b * strideOF + (size_t)r * N + cc] = o;
          e.outBf[(size_t)b * strideOBf + (size_t)r * N + cc] = f2bf(o);
        } else if (EPI == 3) {
          float o = fmaxf(v + e.bias[cc], 0.f);
          e.outBf[(size_t)r * N + cc] = f2bf(o);
        } else {
          float o = fmaxf(v + e.bias[cc], 0.f);
          size_t idx = (size_t)r * N + cc;
          e.outF[idx] = 2.f * e.resid[idx] + o;
        }
      }
    }
  }
}

// ---- out[row] = final[row] / ||final[row]|| ----
__global__ void norm_kernel(const float* __restrict__ fin, float* __restrict__ out) {
  int row = blockIdx.x * 4 + (threadIdx.x >> 6);
  int lane = threadIdx.x & 63;
  const float* p = fin + (size_t)row * Dq;
  float4 v0 = *(const float4*)(p + lane * 8);
  float4 v1 = *(const float4*)(p + lane * 8 + 4);
  float ss = v0.x * v0.x + v0.y * v0.y + v0.z * v0.z + v0.w * v0.w +
             v1.x * v1.x + v1.y * v1.y + v1.z * v1.z + v1.w * v1.w;
#pragma unroll
  for (int o = 32; o; o >>= 1) ss += __shfl_xor(ss, o, 64);
  float rn = 1.f / sqrtf(ss);
  float* q = out + (size_t)row * Dq;
  v0.x *= rn; v0.y *= rn; v0.z *= rn; v0.w *= rn;
  v1.x *= rn; v1.y *= rn; v1.z *= rn; v1.w *= rn;
  *(float4*)(q + lane * 8) = v0;
  *(float4*)(q + lane * 8 + 4) = v1;
}

extern "C" void kernel_launch(void* const* d_in, const int* in_sizes, int n_in,
                              void* d_out, int out_size, void* d_ws, size_t ws_size,
                              hipStream_t stream) {
  const float* inp = (const float*)d_in[0];
  const float* inp_len = (const float*)d_in[1];
  const float* aspect = (const float*)d_in[2];
  const float* w1 = (const float*)d_in[3];
  const float* b1 = (const float*)d_in[4];
  const float* w2 = (const float*)d_in[5];
  const float* b2 = (const float*)d_in[6];
  float* out = (float*)d_out;

  char* W = (char*)d_ws;
  const size_t MB = 1ull << 20;
  unsigned short* inp_bf = (unsigned short*)(W + 0);        // 8 MB  [B][S][D]
  unsigned short* asp_bf = (unsigned short*)(W + 8 * MB);   // 8 MB  [B][S][D]
  unsigned short* inpT   = (unsigned short*)(W + 16 * MB);  // 8 MB  [B][D][S]
  unsigned short* att    = (unsigned short*)(W + 24 * MB);  // 16 MB [B][S][S] (bf16)
  float*          finalF = (float*)(W + 24 * MB);           // 16 MB (reuses att after GEMM2)
  float*          ffnF   = (float*)(W + 40 * MB);           // 16 MB [B*S][D]
  unsigned short* ffnBf  = (unsigned short*)(W + 56 * MB);  // 8 MB
  unsigned short* o1b    = (unsigned short*)(W + 64 * MB);  // 8 MB
  unsigned short* w1bf   = (unsigned short*)(W + 72 * MB);  // 512 KB
  unsigned short* w2bf   = (unsigned short*)(W + 72 * MB + 512 * 1024);
  float*          colsum = (float*)(W + 73 * MB);           // 16 KB
  float*          fac    = (float*)(W + 73 * MB + 64 * 1024);  // 32 KB

  // prep
  hipMemsetAsync(colsum, 0, Bq * Dq * sizeof(float), stream);
  prep_inp<<<dim3(8, 32, 16), dim3(32, 8), 0, stream>>>(inp, inp_bf, inpT, colsum);
  convert_w<<<512, 256, 0, stream>>>(w1, w1bf, w2, w2bf);
  prep_asp<<<2048, 256, 0, stream>>>(aspect, colsum, inp_len, asp_bf, fac);

  // GEMM1: att_n = (aspect . inp) * fac   M=1024 N=1024 K=512  (x=batch -> XCD pin)
  {
    EpiArgs e{};
    e.fac = fac; e.outBf = att;
    gemm_bf16<1, 0><<<dim3(8, 8, 16), 256, 0, stream>>>(
        asp_bf, inp_bf, 1024, 1024, 512,
        (long)Sq * Dq, (long)Sq * Dq, 0, (long)Sq * Sq, e);
  }
  // GEMM2: ffn_inp = att_n @ inp + (inp+aspect)*mask   M=1024 N=512 K=1024
  {
    EpiArgs e{};
    e.inp = inp; e.aspect = aspect; e.lenv = inp_len; e.outF = ffnF; e.outBf = ffnBf;
    gemm_bf16<2, 0><<<dim3(8, 8, 8), 256, 0, stream>>>(
        att, inpT, 1024, 512, 1024,
        (long)Sq * Sq, (long)Dq * Sq, (long)Sq * Dq, (long)Sq * Dq, e);
  }
  // GEMM3: o1 = relu(ffn @ w1^T + b1)   M=8192 N=512 K=512  (x=bm -> XCD pin)
  {
    EpiArgs e{};
    e.bias = b1; e.outBf = o1b;
    gemm_bf16<3, 1><<<dim3(64, 8), 256, 0, stream>>>(
        ffnBf, w1bf, 8192, 512, 512, 0, 0, 0, 0, e);
  }
  // GEMM4: final = 2*ffn + relu(o1 @ w2^T + b2)   M=8192 N=512 K=512
  {
    EpiArgs e{};
    e.bias = b2; e.resid = ffnF; e.outF = finalF;
    gemm_bf16<4, 1><<<dim3(64, 8), 256, 0, stream>>>(
        o1b, w2bf, 8192, 512, 512, 0, 0, 0, 0, e);
  }
  // normalize rows
  norm_kernel<<<2048, 256, 0, stream>>>(finalF, out);
}